// Round 2
// baseline (291.209 us; speedup 1.0000x reference)
//
#include <hip/hip_runtime.h>

typedef __attribute__((ext_vector_type(8))) short short8;
typedef __attribute__((ext_vector_type(4))) float f32x4;

#define T_TOK 16384
#define DM 512
#define NE 8
#define BM 64

__device__ __forceinline__ ushort f2bf(float v) {
  unsigned u = __float_as_uint(v);
  return (ushort)((u + 0x7FFFu + ((u >> 16) & 1u)) >> 16);
}

// ---------------- gating: logits + softmax, one wave per token ----------------
__global__ void gates_kernel(const float* __restrict__ x, const float* __restrict__ Wg,
                             const float* __restrict__ bg, float* __restrict__ gates) {
  int wid = (int)((blockIdx.x * blockDim.x + threadIdx.x) >> 6);
  int lane = threadIdx.x & 63;
  if (wid >= T_TOK) return;
  const float* xt = x + (size_t)wid * DM;
  float a[NE];
#pragma unroll
  for (int e = 0; e < NE; ++e) a[e] = 0.f;
  for (int d = lane; d < DM; d += 64) {
    float xv = xt[d];
    const float* wr = Wg + d * NE;
#pragma unroll
    for (int e = 0; e < NE; ++e) a[e] += xv * wr[e];
  }
#pragma unroll
  for (int e = 0; e < NE; ++e) {
#pragma unroll
    for (int off = 32; off > 0; off >>= 1) a[e] += __shfl_xor(a[e], off, 64);
  }
  float m = -1e30f;
#pragma unroll
  for (int e = 0; e < NE; ++e) { a[e] += bg[e]; m = fmaxf(m, a[e]); }
  float s = 0.f;
#pragma unroll
  for (int e = 0; e < NE; ++e) { a[e] = __expf(a[e] - m); s += a[e]; }
  float inv = 1.f / s;
  if (lane < NE) gates[(size_t)wid * NE + lane] = a[lane] * inv;
}

// -------- weight reorder: W[e][k][n] fp32 -> fragment-major bf16 ------------
// chunk c = ((e*16 + kt)*32 + ntile)*64 + lane; lane l holds
// W[e][kt*32 + (l>>4)*8 + j][ntile*16 + (l&15)] for j=0..7 (bf16).
__global__ void reorder_w_kernel(const float* __restrict__ W, ushort* __restrict__ WF) {
  int c = blockIdx.x * blockDim.x + threadIdx.x;  // 262144 chunks
  int l = c & 63;
  int ntg = (c >> 6) & 31;
  int kt = (c >> 11) & 15;
  int e = c >> 15;
  int n = ntg * 16 + (l & 15);
  int k0 = kt * 32 + (l >> 4) * 8;
  const float* src = W + ((size_t)e * DM + k0) * DM + n;
  short8 v;
#pragma unroll
  for (int j = 0; j < 8; ++j) v[j] = (short)f2bf(src[(size_t)j * DM]);
  *reinterpret_cast<short8*>(WF + (size_t)c * 8) = v;
}

// ---------------- fused MoE main kernel ----------------
// grid = 256 blocks (64 tokens each), 1024 threads = 16 waves.
// Wave w owns output cols [w*32, w*32+32). Both GEMMs computed "swapped":
//   D[f][t] = mfma(A=W-frag, B=x/h-frag)  -> lane holds 4 CONSECUTIVE f/d per fragment.
__global__ __launch_bounds__(1024, 4) void moe_main_kernel(
    const float* __restrict__ x, const ushort* __restrict__ W1F,
    const float* __restrict__ b1, const ushort* __restrict__ W2F,
    const float* __restrict__ b2, const float* __restrict__ gates,
    float* __restrict__ out) {
  extern __shared__ char smem[];
  char* x_lds = smem;                       // 65536 B  [64][512] bf16, XOR-swizzled
  char* h_lds = smem + 65536;               // 65536 B  [64][512] bf16, XOR-swizzled
  float* g_lds = (float*)(smem + 131072);   // 2048 B   [64][8]

  const int tid = threadIdx.x;
  const int lane = tid & 63;
  const int w = tid >> 6;        // wave 0..15
  const int q = lane >> 4;       // 0..3
  const int lr = lane & 15;      // 0..15
  const int m0 = blockIdx.x * BM;
  const int fbase = w * 32;      // this wave's output-column base (f in GEMM1, d in GEMM2)

  if (tid < BM * NE) g_lds[tid] = gates[(size_t)m0 * NE + tid];

  // stage x tile: fp32 -> bf16, XOR-swizzled rows (row stride 1024B)
  for (int i = tid; i < BM * DM / 4; i += 1024) {
    int t = i >> 7;
    int kd = (i & 127) * 4;
    float4 v = *reinterpret_cast<const float4*>(x + ((size_t)(m0 + t) << 9) + kd);
    unsigned lo = (unsigned)f2bf(v.x) | ((unsigned)f2bf(v.y) << 16);
    unsigned hi = (unsigned)f2bf(v.z) | ((unsigned)f2bf(v.w) << 16);
    unsigned off = ((unsigned)(t * 1024 + kd * 2)) ^ (((unsigned)(t & 7)) << 4);
    *reinterpret_cast<uint2*>(x_lds + off) = make_uint2(lo, hi);
  }
  __syncthreads();

  f32x4 acc[2][4];
#pragma unroll
  for (int a_ = 0; a_ < 2; ++a_)
#pragma unroll
    for (int b_ = 0; b_ < 4; ++b_) acc[a_][b_] = (f32x4){0.f, 0.f, 0.f, 0.f};

  for (int e = 0; e < NE; ++e) {
    // ---------- GEMM1: h^T[f][t] = sum_k W1[k][f] * x[t][k] ----------
    const short8* w1p = reinterpret_cast<const short8*>(W1F) + (size_t)e * 32768 + (w * 2) * 64 + lane;
    f32x4 hacc[2][4];
#pragma unroll
    for (int a_ = 0; a_ < 2; ++a_)
#pragma unroll
      for (int b_ = 0; b_ < 4; ++b_) hacc[a_][b_] = (f32x4){0.f, 0.f, 0.f, 0.f};

    short8 wc[2], wn[2];
    wc[0] = w1p[0];
    wc[1] = w1p[64];
#pragma unroll
    for (int kt = 0; kt < 16; ++kt) {
      if (kt < 15) {
        wn[0] = w1p[(kt + 1) * 2048];
        wn[1] = w1p[(kt + 1) * 2048 + 64];
      }
      short8 bf[4];
#pragma unroll
      for (int nt = 0; nt < 4; ++nt) {
        int t = nt * 16 + lr;
        unsigned off = ((unsigned)(t * 1024 + kt * 64 + q * 16)) ^ (((unsigned)(t & 7)) << 4);
        bf[nt] = *reinterpret_cast<const short8*>(x_lds + off);
      }
#pragma unroll
      for (int md = 0; md < 2; ++md)
#pragma unroll
        for (int nt = 0; nt < 4; ++nt)
          hacc[md][nt] = __builtin_amdgcn_mfma_f32_16x16x32_bf16(wc[md], bf[nt], hacc[md][nt], 0, 0, 0);
      if (kt < 15) { wc[0] = wn[0]; wc[1] = wn[1]; }
    }

    // epilogue: h[t][f] = relu(hacc + b1[f]) * g[t]  -> h_lds (bf16, swizzled, b64 writes)
#pragma unroll
    for (int md = 0; md < 2; ++md) {
      int f0 = fbase + md * 16 + q * 4;
      float4 b1q = *reinterpret_cast<const float4*>(b1 + e * DM + f0);
#pragma unroll
      for (int nt = 0; nt < 4; ++nt) {
        int t = nt * 16 + lr;
        float g = g_lds[t * NE + e];
        float v0 = fmaxf(hacc[md][nt][0] + b1q.x, 0.f) * g;
        float v1 = fmaxf(hacc[md][nt][1] + b1q.y, 0.f) * g;
        float v2 = fmaxf(hacc[md][nt][2] + b1q.z, 0.f) * g;
        float v3 = fmaxf(hacc[md][nt][3] + b1q.w, 0.f) * g;
        unsigned lo = (unsigned)f2bf(v0) | ((unsigned)f2bf(v1) << 16);
        unsigned hi = (unsigned)f2bf(v2) | ((unsigned)f2bf(v3) << 16);
        unsigned off = ((unsigned)(t * 1024 + f0 * 2)) ^ (((unsigned)(t & 7)) << 4);
        *reinterpret_cast<uint2*>(h_lds + off) = make_uint2(lo, hi);
      }
    }
    __syncthreads();

    // ---------- GEMM2: out^T[d][t] += sum_f W2[f][d] * h[t][f] ----------
    const short8* w2p = reinterpret_cast<const short8*>(W2F) + (size_t)e * 32768 + (w * 2) * 64 + lane;
    wc[0] = w2p[0];
    wc[1] = w2p[64];
#pragma unroll
    for (int kt = 0; kt < 16; ++kt) {
      if (kt < 15) {
        wn[0] = w2p[(kt + 1) * 2048];
        wn[1] = w2p[(kt + 1) * 2048 + 64];
      }
      short8 bf[4];
#pragma unroll
      for (int nt = 0; nt < 4; ++nt) {
        int t = nt * 16 + lr;
        unsigned off = ((unsigned)(t * 1024 + kt * 64 + q * 16)) ^ (((unsigned)(t & 7)) << 4);
        bf[nt] = *reinterpret_cast<const short8*>(h_lds + off);
      }
#pragma unroll
      for (int md = 0; md < 2; ++md)
#pragma unroll
        for (int nt = 0; nt < 4; ++nt)
          acc[md][nt] = __builtin_amdgcn_mfma_f32_16x16x32_bf16(wc[md], bf[nt], acc[md][nt], 0, 0, 0);
      if (kt < 15) { wc[0] = wn[0]; wc[1] = wn[1]; }
    }

    // fold gate * b2
#pragma unroll
    for (int md = 0; md < 2; ++md) {
      int d0 = fbase + md * 16 + q * 4;
      float4 b2q = *reinterpret_cast<const float4*>(b2 + e * DM + d0);
#pragma unroll
      for (int nt = 0; nt < 4; ++nt) {
        int t = nt * 16 + lr;
        float g = g_lds[t * NE + e];
        acc[md][nt][0] += g * b2q.x;
        acc[md][nt][1] += g * b2q.y;
        acc[md][nt][2] += g * b2q.z;
        acc[md][nt][3] += g * b2q.w;
      }
    }
    __syncthreads();
  }

  // write out (fp32, float4 per fragment: lane holds 4 consecutive d for row t)
#pragma unroll
  for (int md = 0; md < 2; ++md) {
    int d0 = fbase + md * 16 + q * 4;
#pragma unroll
    for (int nt = 0; nt < 4; ++nt) {
      int t = nt * 16 + lr;
      *reinterpret_cast<f32x4*>(out + ((size_t)(m0 + t)) * DM + d0) = acc[md][nt];
    }
  }
}

extern "C" void kernel_launch(void* const* d_in, const int* in_sizes, int n_in,
                              void* d_out, int out_size, void* d_ws, size_t ws_size,
                              hipStream_t stream) {
  const float* x  = (const float*)d_in[0];
  const float* W1 = (const float*)d_in[1];
  const float* b1 = (const float*)d_in[2];
  const float* W2 = (const float*)d_in[3];
  const float* b2 = (const float*)d_in[4];
  const float* Wg = (const float*)d_in[5];
  const float* bg = (const float*)d_in[6];
  float* out = (float*)d_out;

  float* gates = (float*)d_ws;                              // 524288 B
  ushort* W1F = (ushort*)((char*)d_ws + 524288);            // 4 MiB
  ushort* W2F = (ushort*)((char*)d_ws + 524288 + 4194304);  // 4 MiB

  // allow >64KB dynamic LDS (host-side attribute, graph-capture-safe)
  hipFuncSetAttribute((const void*)moe_main_kernel,
                      hipFuncAttributeMaxDynamicSharedMemorySize, 133120);

  gates_kernel<<<T_TOK / 4, 256, 0, stream>>>(x, Wg, bg, gates);
  reorder_w_kernel<<<1024, 256, 0, stream>>>(W1, W1F);
  reorder_w_kernel<<<1024, 256, 0, stream>>>(W2, W2F);
  moe_main_kernel<<<T_TOK / BM, 1024, 133120, stream>>>(x, W1F, b1, W2F, b2, gates, out);
}

// Round 3
// 202.389 us; speedup vs baseline: 1.4389x; 1.4389x over previous
//
#include <hip/hip_runtime.h>

typedef __attribute__((ext_vector_type(8))) short short8;
typedef __attribute__((ext_vector_type(4))) float f32x4;
typedef __attribute__((ext_vector_type(16))) float f32x16;

#define T_TOK 16384
#define DM 512
#define NE 8
#define BM 64

__device__ __forceinline__ ushort f2bf(float v) {
  unsigned u = __float_as_uint(v);
  return (ushort)((u + 0x7FFFu + ((u >> 16) & 1u)) >> 16);
}

// ---------------- gating: logits + softmax, one wave per token ----------------
__global__ void gates_kernel(const float* __restrict__ x, const float* __restrict__ Wg,
                             const float* __restrict__ bg, float* __restrict__ gates) {
  int wid = (int)((blockIdx.x * blockDim.x + threadIdx.x) >> 6);
  int lane = threadIdx.x & 63;
  if (wid >= T_TOK) return;
  const float* xt = x + (size_t)wid * DM;
  float a[NE];
#pragma unroll
  for (int e = 0; e < NE; ++e) a[e] = 0.f;
  for (int d = lane; d < DM; d += 64) {
    float xv = xt[d];
    const float* wr = Wg + d * NE;
#pragma unroll
    for (int e = 0; e < NE; ++e) a[e] += xv * wr[e];
  }
#pragma unroll
  for (int e = 0; e < NE; ++e) {
#pragma unroll
    for (int off = 32; off > 0; off >>= 1) a[e] += __shfl_xor(a[e], off, 64);
  }
  float m = -1e30f;
#pragma unroll
  for (int e = 0; e < NE; ++e) { a[e] += bg[e]; m = fmaxf(m, a[e]); }
  float s = 0.f;
#pragma unroll
  for (int e = 0; e < NE; ++e) { a[e] = __expf(a[e] - m); s += a[e]; }
  float inv = 1.f / s;
  if (lane < NE) gates[(size_t)wid * NE + lane] = a[lane] * inv;
}

// -------- weight reorder: W[e][k][n] fp32 -> 32x32x16 A-fragment-major bf16 ----
// chunkid = (e*32 + kh)*16 + ft ; lane l holds
// W[e][kh*16 + (l>>5)*8 + j][ft*32 + (l&31)]  for j=0..7 (bf16).
__global__ void reorder_w_kernel(const float* __restrict__ W, ushort* __restrict__ WF) {
  int c = blockIdx.x * blockDim.x + threadIdx.x;  // 262144 threads
  int l = c & 63;
  int chunk = c >> 6;
  int ft = chunk & 15;
  int kh = (chunk >> 4) & 31;
  int e = chunk >> 9;
  int n = ft * 32 + (l & 31);
  int k0 = kh * 16 + (l >> 5) * 8;
  const float* src = W + ((size_t)e * DM + k0) * DM + n;
  short8 v;
#pragma unroll
  for (int j = 0; j < 8; ++j) v[j] = (short)f2bf(src[(size_t)j * DM]);
  *reinterpret_cast<short8*>(WF + (size_t)c * 8) = v;
}

// ---------------- fused MoE main kernel ----------------
// 256 blocks x 512 threads (8 waves). Wave w owns output cols [w*64, w*64+64).
// 32x32x16 MFMA, swapped operands: D[f][t] = mfma(A=W-frag, B=act-frag).
__global__ __launch_bounds__(512, 2) void moe_main_kernel(
    const float* __restrict__ x, const ushort* __restrict__ W1F,
    const float* __restrict__ b1, const ushort* __restrict__ W2F,
    const float* __restrict__ b2, const float* __restrict__ gates,
    float* __restrict__ out) {
  extern __shared__ char smem[];
  char* x_lds = smem;                       // 65536 B  [64][512] bf16, XOR-swizzled
  char* h_lds = smem + 65536;               // 65536 B  [64][512] bf16, XOR-swizzled
  float* g_lds = (float*)(smem + 131072);   // [64][9] f32 (pad 9 -> conflict-free)

  const int tid = threadIdx.x;
  const int lane = tid & 63;
  const int w = tid >> 6;        // wave 0..7
  const int hi = lane >> 5;      // k-half
  const int l31 = lane & 31;
  const int m0 = blockIdx.x * BM;
  const unsigned arow = (unsigned)l31 * 1024;
  const unsigned swz = ((unsigned)(l31 & 7)) << 4;
  const unsigned hi16 = (unsigned)hi * 16;

  {  // gates -> LDS (padded stride 9)
    int t = tid >> 3, e = tid & 7;
    g_lds[t * 9 + e] = gates[(size_t)(m0 + t) * NE + e];
  }

  // stage x tile: fp32 -> bf16, XOR-swizzled rows (row stride 1024B)
  for (int i = tid; i < BM * DM / 4; i += 512) {
    int t = i >> 7;
    int kd = (i & 127) * 4;
    float4 v = *reinterpret_cast<const float4*>(x + ((size_t)(m0 + t) << 9) + kd);
    unsigned lo = (unsigned)f2bf(v.x) | ((unsigned)f2bf(v.y) << 16);
    unsigned hb = (unsigned)f2bf(v.z) | ((unsigned)f2bf(v.w) << 16);
    unsigned off = (unsigned)(t * 1024) + (((unsigned)(kd * 2)) ^ (((unsigned)(t & 7)) << 4));
    *reinterpret_cast<uint2*>(x_lds + off) = make_uint2(lo, hb);
  }
  __syncthreads();

  // act-fragment load: 16B at row (ni*32+l31), col bytes kt*64+ks*32+hi*16 (^swz)
#define LDACT(lds, kt, ks, ni) \
  (*reinterpret_cast<const short8*>((lds) + arow + (ni) * 32768 + \
      (((unsigned)((kt) * 64 + (ks) * 32) + hi16) ^ swz)))

#define MF(d, a, b) d = __builtin_amdgcn_mfma_f32_32x32x16_bf16(a, b, d, 0, 0, 0)

  const short8* wp1 = reinterpret_cast<const short8*>(W1F) + w * 128 + lane;
  const short8* wp2 = reinterpret_cast<const short8*>(W2F) + w * 128 + lane;

  f32x16 acc[2][2];
#pragma unroll
  for (int mi = 0; mi < 2; ++mi)
#pragma unroll
    for (int ni = 0; ni < 2; ++ni)
#pragma unroll
      for (int i = 0; i < 16; ++i) acc[mi][ni][i] = 0.f;

  short8 wb[3][4], ab[2][4];

  // e=0 GEMM1 prologue: kt0 -> wb[2], kt1 -> wb[0]; act kt0 -> ab[0]
#pragma unroll
  for (int ks = 0; ks < 2; ++ks)
#pragma unroll
    for (int mi = 0; mi < 2; ++mi) {
      wb[2][ks * 2 + mi] = wp1[ks * 1024 + mi * 64];
      wb[0][ks * 2 + mi] = wp1[2048 + ks * 1024 + mi * 64];
    }
#pragma unroll
  for (int ks = 0; ks < 2; ++ks)
#pragma unroll
    for (int ni = 0; ni < 2; ++ni) ab[0][ks * 2 + ni] = LDACT(x_lds, 0, ks, ni);

  for (int e = 0; e < NE; ++e) {
    const short8* we1 = wp1 + (size_t)e * 32768;
    const short8* we2 = wp2 + (size_t)e * 32768;

    // ---------- GEMM1: h^T[f][t] = sum_k W1[k][f] * x[t][k] ----------
    f32x16 hacc[2][2];
#pragma unroll
    for (int mi = 0; mi < 2; ++mi)
#pragma unroll
      for (int ni = 0; ni < 2; ++ni)
#pragma unroll
        for (int i = 0; i < 16; ++i) hacc[mi][ni][i] = 0.f;

#pragma unroll
    for (int kt = 0; kt < 16; ++kt) {
      if (kt < 14) {
#pragma unroll
        for (int ks = 0; ks < 2; ++ks)
#pragma unroll
          for (int mi = 0; mi < 2; ++mi)
            wb[(kt + 1) % 3][ks * 2 + mi] = we1[(kt + 2) * 2048 + ks * 1024 + mi * 64];
      }
      if (kt < 15) {
#pragma unroll
        for (int ks = 0; ks < 2; ++ks)
#pragma unroll
          for (int ni = 0; ni < 2; ++ni)
            ab[(kt + 1) % 2][ks * 2 + ni] = LDACT(x_lds, kt + 1, ks, ni);
      }
#pragma unroll
      for (int ks = 0; ks < 2; ++ks)
#pragma unroll
        for (int mi = 0; mi < 2; ++mi)
#pragma unroll
          for (int ni = 0; ni < 2; ++ni)
            MF(hacc[mi][ni], wb[(kt + 2) % 3][ks * 2 + mi], ab[kt % 2][ks * 2 + ni]);
    }

    // GEMM2 weight prologue (overlaps epilogue + barrier): kt0 -> wb[1], kt1 -> wb[2]
#pragma unroll
    for (int ks = 0; ks < 2; ++ks)
#pragma unroll
      for (int mi = 0; mi < 2; ++mi) {
        wb[1][ks * 2 + mi] = we2[ks * 1024 + mi * 64];
        wb[2][ks * 2 + mi] = we2[2048 + ks * 1024 + mi * 64];
      }

    // epilogue: h[t][f] = relu(hacc + b1[f]) * g[t] -> h_lds (b64 writes)
#pragma unroll
    for (int ni = 0; ni < 2; ++ni) {
      int t = ni * 32 + l31;
      float g = g_lds[t * 9 + e];
#pragma unroll
      for (int mi = 0; mi < 2; ++mi) {
#pragma unroll
        for (int j = 0; j < 4; ++j) {
          int f = w * 64 + mi * 32 + j * 8 + hi * 4;
          float4 b1q = *reinterpret_cast<const float4*>(b1 + e * DM + f);
          float v0 = fmaxf(hacc[mi][ni][j * 4 + 0] + b1q.x, 0.f) * g;
          float v1 = fmaxf(hacc[mi][ni][j * 4 + 1] + b1q.y, 0.f) * g;
          float v2 = fmaxf(hacc[mi][ni][j * 4 + 2] + b1q.z, 0.f) * g;
          float v3 = fmaxf(hacc[mi][ni][j * 4 + 3] + b1q.w, 0.f) * g;
          unsigned lo = (unsigned)f2bf(v0) | ((unsigned)f2bf(v1) << 16);
          unsigned hb = (unsigned)f2bf(v2) | ((unsigned)f2bf(v3) << 16);
          unsigned off = (unsigned)(t * 1024) +
                         (((unsigned)(f * 2)) ^ (((unsigned)(t & 7)) << 4));
          *reinterpret_cast<uint2*>(h_lds + off) = make_uint2(lo, hb);
        }
      }
    }
    __syncthreads();

    // ---------- GEMM2: acc[d][t] += sum_f W2[f][d] * h[t][f] ----------
#pragma unroll
    for (int ks = 0; ks < 2; ++ks)
#pragma unroll
      for (int ni = 0; ni < 2; ++ni) ab[0][ks * 2 + ni] = LDACT(h_lds, 0, ks, ni);

#pragma unroll
    for (int kt = 0; kt < 16; ++kt) {
      if (kt < 14) {
#pragma unroll
        for (int ks = 0; ks < 2; ++ks)
#pragma unroll
          for (int mi = 0; mi < 2; ++mi)
            wb[kt % 3][ks * 2 + mi] = we2[(kt + 2) * 2048 + ks * 1024 + mi * 64];
      }
      if (kt < 15) {
#pragma unroll
        for (int ks = 0; ks < 2; ++ks)
#pragma unroll
          for (int ni = 0; ni < 2; ++ni)
            ab[(kt + 1) % 2][ks * 2 + ni] = LDACT(h_lds, kt + 1, ks, ni);
      }
#pragma unroll
      for (int ks = 0; ks < 2; ++ks)
#pragma unroll
        for (int mi = 0; mi < 2; ++mi)
#pragma unroll
          for (int ni = 0; ni < 2; ++ni)
            MF(acc[mi][ni], wb[(kt + 1) % 3][ks * 2 + mi], ab[kt % 2][ks * 2 + ni]);
    }

    // next-expert GEMM1 prologue (overlaps b2-fold + barrier)
    if (e < NE - 1) {
      const short8* wn1 = we1 + 32768;
#pragma unroll
      for (int ks = 0; ks < 2; ++ks)
#pragma unroll
        for (int mi = 0; mi < 2; ++mi) {
          wb[2][ks * 2 + mi] = wn1[ks * 1024 + mi * 64];
          wb[0][ks * 2 + mi] = wn1[2048 + ks * 1024 + mi * 64];
        }
#pragma unroll
      for (int ks = 0; ks < 2; ++ks)
#pragma unroll
        for (int ni = 0; ni < 2; ++ni) ab[0][ks * 2 + ni] = LDACT(x_lds, 0, ks, ni);
    }

    // fold gate * b2
#pragma unroll
    for (int ni = 0; ni < 2; ++ni) {
      int t = ni * 32 + l31;
      float g = g_lds[t * 9 + e];
#pragma unroll
      for (int mi = 0; mi < 2; ++mi)
#pragma unroll
        for (int j = 0; j < 4; ++j) {
          float4 b2q = *reinterpret_cast<const float4*>(b2 + e * DM + w * 64 + mi * 32 + j * 8 + hi * 4);
          acc[mi][ni][j * 4 + 0] += g * b2q.x;
          acc[mi][ni][j * 4 + 1] += g * b2q.y;
          acc[mi][ni][j * 4 + 2] += g * b2q.z;
          acc[mi][ni][j * 4 + 3] += g * b2q.w;
        }
    }
    __syncthreads();
  }

  // write out: per (mi,ni,j) a float4 of consecutive d
#pragma unroll
  for (int ni = 0; ni < 2; ++ni) {
    int t = m0 + ni * 32 + l31;
#pragma unroll
    for (int mi = 0; mi < 2; ++mi)
#pragma unroll
      for (int j = 0; j < 4; ++j) {
        f32x4 v;
        v[0] = acc[mi][ni][j * 4 + 0];
        v[1] = acc[mi][ni][j * 4 + 1];
        v[2] = acc[mi][ni][j * 4 + 2];
        v[3] = acc[mi][ni][j * 4 + 3];
        *reinterpret_cast<f32x4*>(out + (size_t)t * DM + w * 64 + mi * 32 + j * 8 + hi * 4) = v;
      }
  }
#undef LDACT
#undef MF
}

extern "C" void kernel_launch(void* const* d_in, const int* in_sizes, int n_in,
                              void* d_out, int out_size, void* d_ws, size_t ws_size,
                              hipStream_t stream) {
  const float* x  = (const float*)d_in[0];
  const float* W1 = (const float*)d_in[1];
  const float* b1 = (const float*)d_in[2];
  const float* W2 = (const float*)d_in[3];
  const float* b2 = (const float*)d_in[4];
  const float* Wg = (const float*)d_in[5];
  const float* bg = (const float*)d_in[6];
  float* out = (float*)d_out;

  float* gates = (float*)d_ws;                              // 524288 B
  ushort* W1F = (ushort*)((char*)d_ws + 524288);            // 4 MiB
  ushort* W2F = (ushort*)((char*)d_ws + 524288 + 4194304);  // 4 MiB

  hipFuncSetAttribute((const void*)moe_main_kernel,
                      hipFuncAttributeMaxDynamicSharedMemorySize, 133376);

  gates_kernel<<<T_TOK / 4, 256, 0, stream>>>(x, Wg, bg, gates);
  reorder_w_kernel<<<1024, 256, 0, stream>>>(W1, W1F);
  reorder_w_kernel<<<1024, 256, 0, stream>>>(W2, W2F);
  moe_main_kernel<<<T_TOK / BM, 512, 133376, stream>>>(x, W1F, b1, W2F, b2, gates, out);
}

// Round 4
// 167.794 us; speedup vs baseline: 1.7355x; 1.2062x over previous
//
#include <hip/hip_runtime.h>

typedef __attribute__((ext_vector_type(8))) short short8;
typedef __attribute__((ext_vector_type(4))) float f32x4;
typedef __attribute__((ext_vector_type(16))) float f32x16;

#define T_TOK 16384
#define DM 512
#define NE 8
#define BM 64
#define ROWB 1040  // padded LDS row stride: 65*16B -> bank-slot rotates by 1/row

__device__ __forceinline__ ushort f2bf(float v) {
  unsigned u = __float_as_uint(v);
  return (ushort)((u + 0x7FFFu + ((u >> 16) & 1u)) >> 16);
}

// ---------------- gating: logits + softmax, one wave per token ----------------
__global__ void gates_kernel(const float* __restrict__ x, const float* __restrict__ Wg,
                             const float* __restrict__ bg, float* __restrict__ gates) {
  int wid = (int)((blockIdx.x * blockDim.x + threadIdx.x) >> 6);
  int lane = threadIdx.x & 63;
  if (wid >= T_TOK) return;
  const float* xt = x + (size_t)wid * DM;
  float a[NE];
#pragma unroll
  for (int e = 0; e < NE; ++e) a[e] = 0.f;
  for (int d = lane; d < DM; d += 64) {
    float xv = xt[d];
    const float* wr = Wg + d * NE;
#pragma unroll
    for (int e = 0; e < NE; ++e) a[e] += xv * wr[e];
  }
#pragma unroll
  for (int e = 0; e < NE; ++e) {
#pragma unroll
    for (int off = 32; off > 0; off >>= 1) a[e] += __shfl_xor(a[e], off, 64);
  }
  float m = -1e30f;
#pragma unroll
  for (int e = 0; e < NE; ++e) { a[e] += bg[e]; m = fmaxf(m, a[e]); }
  float s = 0.f;
#pragma unroll
  for (int e = 0; e < NE; ++e) { a[e] = __expf(a[e] - m); s += a[e]; }
  float inv = 1.f / s;
  if (lane < NE) gates[(size_t)wid * NE + lane] = a[lane] * inv;
}

// -------- weight reorder: W[e][k][n] fp32 -> 32x32x16 A-fragment-major bf16 ----
// chunkid = (e*32 + kh)*16 + ft ; lane l holds
// W[e][kh*16 + (l>>5)*8 + j][ft*32 + (l&31)]  for j=0..7 (bf16).
__global__ void reorder_w_kernel(const float* __restrict__ W, ushort* __restrict__ WF) {
  int c = blockIdx.x * blockDim.x + threadIdx.x;  // 262144 threads
  int l = c & 63;
  int chunk = c >> 6;
  int ft = chunk & 15;
  int kh = (chunk >> 4) & 31;
  int e = chunk >> 9;
  int n = ft * 32 + (l & 31);
  int k0 = kh * 16 + (l >> 5) * 8;
  const float* src = W + ((size_t)e * DM + k0) * DM + n;
  short8 v;
#pragma unroll
  for (int j = 0; j < 8; ++j) v[j] = (short)f2bf(src[(size_t)j * DM]);
  *reinterpret_cast<short8*>(WF + (size_t)c * 8) = v;
}

// ---------------- fused MoE main kernel ----------------
// 256 blocks x 512 threads (8 waves). Wave w owns output cols [w*64, w*64+64).
// 32x32x16 MFMA, swapped operands: D[f][t] = mfma(A=W-frag, B=act-frag).
// Raw s_barrier + lgkmcnt-only drain: weight prefetches stay in flight
// across barriers. Padded LDS rows (1040B) -> conflict-free, additive addressing.
__global__ __launch_bounds__(512, 2) void moe_main_kernel(
    const float* __restrict__ x, const ushort* __restrict__ W1F,
    const float* __restrict__ b1, const ushort* __restrict__ W2F,
    const float* __restrict__ b2, const float* __restrict__ gates,
    float* __restrict__ out) {
  extern __shared__ char smem[];
  char* x_lds = smem;                        // 64 rows * 1040 B = 66560
  char* h_lds = smem + 66560;                // 66560
  float* g_lds = (float*)(smem + 133120);    // [64][9] f32

  const int tid = threadIdx.x;
  const int lane = tid & 63;
  const int w = tid >> 6;        // wave 0..7
  const int hi = lane >> 5;      // k-half
  const int l31 = lane & 31;
  const int m0 = blockIdx.x * BM;

  // act-fragment base: row (ni*32 + l31), col byte hi*16; +kt*64 +ks*32 folds to imm
  const unsigned abase = (unsigned)l31 * ROWB + (unsigned)hi * 16;
  // h-epilogue write base: row l31, col byte (w*64 + hi*4)*2
  const unsigned wbase = (unsigned)l31 * ROWB + (unsigned)(w * 128 + hi * 8);

#define BARRIER()                                        \
  do {                                                   \
    asm volatile("s_waitcnt lgkmcnt(0)" ::: "memory");   \
    __builtin_amdgcn_s_barrier();                        \
  } while (0)

  {  // gates -> LDS (padded stride 9)
    int t = tid >> 3, e = tid & 7;
    g_lds[t * 9 + e] = gates[(size_t)(m0 + t) * NE + e];
  }

  // stage x tile: fp32 -> bf16, padded rows
  for (int i = tid; i < BM * DM / 4; i += 512) {
    int t = i >> 7;
    int kd = (i & 127) * 4;
    float4 v = *reinterpret_cast<const float4*>(x + ((size_t)(m0 + t) << 9) + kd);
    unsigned lo = (unsigned)f2bf(v.x) | ((unsigned)f2bf(v.y) << 16);
    unsigned hb = (unsigned)f2bf(v.z) | ((unsigned)f2bf(v.w) << 16);
    *reinterpret_cast<uint2*>(x_lds + (unsigned)(t * ROWB + kd * 2)) = make_uint2(lo, hb);
  }
  BARRIER();

#define LDACT(lds, kt, ks, ni) \
  (*reinterpret_cast<const short8*>((lds) + abase + (ni) * (32 * ROWB) + ((kt) * 64 + (ks) * 32)))

#define MF(d, a, b) d = __builtin_amdgcn_mfma_f32_32x32x16_bf16(a, b, d, 0, 0, 0)

  const short8* wp1 = reinterpret_cast<const short8*>(W1F) + w * 128 + lane;
  const short8* wp2 = reinterpret_cast<const short8*>(W2F) + w * 128 + lane;

  f32x16 acc[2][2];
#pragma unroll
  for (int mi = 0; mi < 2; ++mi)
#pragma unroll
    for (int ni = 0; ni < 2; ++ni)
#pragma unroll
      for (int i = 0; i < 16; ++i) acc[mi][ni][i] = 0.f;

  short8 wb[3][4], ab[2][4];

  // e=0 GEMM1 prologue: kt0 -> wb[2], kt1 -> wb[0]; act kt0 -> ab[0]
#pragma unroll
  for (int ks = 0; ks < 2; ++ks)
#pragma unroll
    for (int mi = 0; mi < 2; ++mi) {
      wb[2][ks * 2 + mi] = wp1[ks * 1024 + mi * 64];
      wb[0][ks * 2 + mi] = wp1[2048 + ks * 1024 + mi * 64];
    }
#pragma unroll
  for (int ks = 0; ks < 2; ++ks)
#pragma unroll
    for (int ni = 0; ni < 2; ++ni) ab[0][ks * 2 + ni] = LDACT(x_lds, 0, ks, ni);

  for (int e = 0; e < NE; ++e) {
    const short8* we1 = wp1 + (size_t)e * 32768;
    const short8* we2 = wp2 + (size_t)e * 32768;

    // ---------- GEMM1: h^T[f][t] = sum_k W1[k][f] * x[t][k] ----------
    f32x16 hacc[2][2];
#pragma unroll
    for (int mi = 0; mi < 2; ++mi)
#pragma unroll
      for (int ni = 0; ni < 2; ++ni)
#pragma unroll
        for (int i = 0; i < 16; ++i) hacc[mi][ni][i] = 0.f;

#pragma unroll
    for (int kt = 0; kt < 16; ++kt) {
      if (kt < 14) {
#pragma unroll
        for (int ks = 0; ks < 2; ++ks)
#pragma unroll
          for (int mi = 0; mi < 2; ++mi)
            wb[(kt + 1) % 3][ks * 2 + mi] = we1[(kt + 2) * 2048 + ks * 1024 + mi * 64];
      }
      if (kt < 15) {
#pragma unroll
        for (int ks = 0; ks < 2; ++ks)
#pragma unroll
          for (int ni = 0; ni < 2; ++ni)
            ab[(kt + 1) % 2][ks * 2 + ni] = LDACT(x_lds, kt + 1, ks, ni);
      }
      __builtin_amdgcn_s_setprio(1);
#pragma unroll
      for (int ks = 0; ks < 2; ++ks)
#pragma unroll
        for (int mi = 0; mi < 2; ++mi)
#pragma unroll
          for (int ni = 0; ni < 2; ++ni)
            MF(hacc[mi][ni], wb[(kt + 2) % 3][ks * 2 + mi], ab[kt % 2][ks * 2 + ni]);
      __builtin_amdgcn_s_setprio(0);
    }

    // GEMM2 weight prologue (stays in flight across barrier): kt0 -> wb[1], kt1 -> wb[2]
#pragma unroll
    for (int ks = 0; ks < 2; ++ks)
#pragma unroll
      for (int mi = 0; mi < 2; ++mi) {
        wb[1][ks * 2 + mi] = we2[ks * 1024 + mi * 64];
        wb[2][ks * 2 + mi] = we2[2048 + ks * 1024 + mi * 64];
      }

    // epilogue: h[t][f] = relu(hacc + b1[f]) * g[t] -> h_lds (b64 writes)
#pragma unroll
    for (int ni = 0; ni < 2; ++ni) {
      int t = ni * 32 + l31;
      float g = g_lds[t * 9 + e];
#pragma unroll
      for (int mi = 0; mi < 2; ++mi) {
#pragma unroll
        for (int j = 0; j < 4; ++j) {
          float4 b1q = *reinterpret_cast<const float4*>(
              b1 + e * DM + w * 64 + mi * 32 + j * 8 + hi * 4);
          float v0 = fmaxf(hacc[mi][ni][j * 4 + 0] + b1q.x, 0.f) * g;
          float v1 = fmaxf(hacc[mi][ni][j * 4 + 1] + b1q.y, 0.f) * g;
          float v2 = fmaxf(hacc[mi][ni][j * 4 + 2] + b1q.z, 0.f) * g;
          float v3 = fmaxf(hacc[mi][ni][j * 4 + 3] + b1q.w, 0.f) * g;
          unsigned lo = (unsigned)f2bf(v0) | ((unsigned)f2bf(v1) << 16);
          unsigned hb = (unsigned)f2bf(v2) | ((unsigned)f2bf(v3) << 16);
          *reinterpret_cast<uint2*>(h_lds + wbase + ni * (32 * ROWB) + mi * 64 + j * 16) =
              make_uint2(lo, hb);
        }
      }
    }
    BARRIER();

    // ---------- GEMM2: acc[d][t] += sum_f W2[f][d] * h[t][f] ----------
#pragma unroll
    for (int ks = 0; ks < 2; ++ks)
#pragma unroll
      for (int ni = 0; ni < 2; ++ni) ab[0][ks * 2 + ni] = LDACT(h_lds, 0, ks, ni);

#pragma unroll
    for (int kt = 0; kt < 16; ++kt) {
      if (kt < 14) {
#pragma unroll
        for (int ks = 0; ks < 2; ++ks)
#pragma unroll
          for (int mi = 0; mi < 2; ++mi)
            wb[kt % 3][ks * 2 + mi] = we2[(kt + 2) * 2048 + ks * 1024 + mi * 64];
      }
      if (kt < 15) {
#pragma unroll
        for (int ks = 0; ks < 2; ++ks)
#pragma unroll
          for (int ni = 0; ni < 2; ++ni)
            ab[(kt + 1) % 2][ks * 2 + ni] = LDACT(h_lds, kt + 1, ks, ni);
      }
      __builtin_amdgcn_s_setprio(1);
#pragma unroll
      for (int ks = 0; ks < 2; ++ks)
#pragma unroll
        for (int mi = 0; mi < 2; ++mi)
#pragma unroll
          for (int ni = 0; ni < 2; ++ni)
            MF(acc[mi][ni], wb[(kt + 1) % 3][ks * 2 + mi], ab[kt % 2][ks * 2 + ni]);
      __builtin_amdgcn_s_setprio(0);
    }

    // next-expert GEMM1 prologue (stays in flight across barrier)
    if (e < NE - 1) {
      const short8* wn1 = we1 + 32768;
#pragma unroll
      for (int ks = 0; ks < 2; ++ks)
#pragma unroll
        for (int mi = 0; mi < 2; ++mi) {
          wb[2][ks * 2 + mi] = wn1[ks * 1024 + mi * 64];
          wb[0][ks * 2 + mi] = wn1[2048 + ks * 1024 + mi * 64];
        }
#pragma unroll
      for (int ks = 0; ks < 2; ++ks)
#pragma unroll
        for (int ni = 0; ni < 2; ++ni) ab[0][ks * 2 + ni] = LDACT(x_lds, 0, ks, ni);
    }

    // fold gate * b2
#pragma unroll
    for (int ni = 0; ni < 2; ++ni) {
      int t = ni * 32 + l31;
      float g = g_lds[t * 9 + e];
#pragma unroll
      for (int mi = 0; mi < 2; ++mi)
#pragma unroll
        for (int j = 0; j < 4; ++j) {
          float4 b2q = *reinterpret_cast<const float4*>(
              b2 + e * DM + w * 64 + mi * 32 + j * 8 + hi * 4);
          acc[mi][ni][j * 4 + 0] += g * b2q.x;
          acc[mi][ni][j * 4 + 1] += g * b2q.y;
          acc[mi][ni][j * 4 + 2] += g * b2q.z;
          acc[mi][ni][j * 4 + 3] += g * b2q.w;
        }
    }
    BARRIER();
  }

  // write out: per (mi,ni,j) a float4 of consecutive d
#pragma unroll
  for (int ni = 0; ni < 2; ++ni) {
    int t = m0 + ni * 32 + l31;
#pragma unroll
    for (int mi = 0; mi < 2; ++mi)
#pragma unroll
      for (int j = 0; j < 4; ++j) {
        f32x4 v;
        v[0] = acc[mi][ni][j * 4 + 0];
        v[1] = acc[mi][ni][j * 4 + 1];
        v[2] = acc[mi][ni][j * 4 + 2];
        v[3] = acc[mi][ni][j * 4 + 3];
        *reinterpret_cast<f32x4*>(out + (size_t)t * DM + w * 64 + mi * 32 + j * 8 + hi * 4) = v;
      }
  }
#undef LDACT
#undef MF
#undef BARRIER
}

extern "C" void kernel_launch(void* const* d_in, const int* in_sizes, int n_in,
                              void* d_out, int out_size, void* d_ws, size_t ws_size,
                              hipStream_t stream) {
  const float* x  = (const float*)d_in[0];
  const float* W1 = (const float*)d_in[1];
  const float* b1 = (const float*)d_in[2];
  const float* W2 = (const float*)d_in[3];
  const float* b2 = (const float*)d_in[4];
  const float* Wg = (const float*)d_in[5];
  const float* bg = (const float*)d_in[6];
  float* out = (float*)d_out;

  float* gates = (float*)d_ws;                              // 524288 B
  ushort* W1F = (ushort*)((char*)d_ws + 524288);            // 4 MiB
  ushort* W2F = (ushort*)((char*)d_ws + 524288 + 4194304);  // 4 MiB

  hipFuncSetAttribute((const void*)moe_main_kernel,
                      hipFuncAttributeMaxDynamicSharedMemorySize, 135424);

  gates_kernel<<<T_TOK / 4, 256, 0, stream>>>(x, Wg, bg, gates);
  reorder_w_kernel<<<1024, 256, 0, stream>>>(W1, W1F);
  reorder_w_kernel<<<1024, 256, 0, stream>>>(W2, W2F);
  moe_main_kernel<<<T_TOK / BM, 512, 135424, stream>>>(x, W1F, b1, W2F, b2, gates, out);
}